// Round 8
// baseline (205.724 us; speedup 1.0000x reference)
//
#include <hip/hip_runtime.h>
#include <math.h>

#define HW      268324      // 518*518
#define HW4     67081       // HW/4 (pixel-quads per frame)
#define T_      32
#define B_      2
#define NPAIR   31          // T-1
#define NROW    62          // B*(T-1)
#define GX      263         // x-blocks: ceil(HW4/256)
#define CHUNKS  8           // frame-chunks per batch
#define NBLKB   (CHUNKS*GX) // partial-blocks per batch
#define NFC     5           // frames read per chunk (4 owned + 1 overlap)
#define CAP     2048        // per-row static-pixel capacity (~215 expected)
#define CSTR    16          // cnt stride in ints (64B line per counter)
#define EPSF    1e-6f
#define STH     0.05f

// native clang vector types — required by __builtin_nontemporal_load
typedef float fx4 __attribute__((ext_vector_type(4)));
typedef int   ix4 __attribute__((ext_vector_type(4)));

// ---- workspace layout (bytes) ----
// 64     : int    cnt[NROW*CSTR]        (zeroed by memset)   [64, 4032)
// 8192   : double partials[16*GX][5]                         [8192, 176512)
// 180224 : float  rbuf[NROW*CAP]
// 688128 : float  gbuf[NROW*CAP]

// reciprocal: v_rcp_f32 + 1 Newton step (~1 ulp); tolerance is 2% relative
__device__ __forceinline__ float fast_rcp(float x) {
    float r = __builtin_amdgcn_rcpf(x);
    float e = fmaf(-x, r, 1.0f);
    return fmaf(r, e, r);
}

// NT loads: proven in every best config; duration is HBM-independent (warm
// L3 replays take the same time), so streaming no-allocate is right.
__device__ __forceinline__ fx4 nt_load4(const float* p) {
    return __builtin_nontemporal_load((const fx4*)p);
}
__device__ __forceinline__ ix4 nt_load4i(const int* p) {
    return __builtin_nontemporal_load((const ix4*)p);
}
__device__ __forceinline__ unsigned int nt_loadu(const unsigned char* p) {
    return __builtin_nontemporal_load((const unsigned int*)p);
}

// Eighth-chunk pass1 with FULL-CHUNK prefetch: each block owns 4 frames,
// reads 5 (1.25x redundancy), and loads ALL 5 frames' data up-front with
// static indices — no rotating slots, no modulo. 45 dwords in flight/thread
// gives depth-5 pipelining via the compiler's natural vmcnt interleave.
// r6/r7 decomposition showed rate = waves x per-wave-MLP and the register
// allocator kept trading one for the other (r7: VGPR 60 = serialized
// prefetch at 28% occupancy; r6: 104 VGPR depth-3 at 15% occupancy). This
// config is the first to maximize both: straight-line loads the allocator
// demonstrably keeps in registers (r0/r6 pattern), and 4208 blocks = 65.8
// waves/CU of work.
//
// TOOLCHAIN LANDMINE (r3/r4/r5-measured): a min-waves 2nd launch_bounds arg
// makes the backend chase ~2x the requested occupancy and spill the loop
// body. Single-arg launch_bounds(256) is safe.
//
// Chunk c of batch b reads frames [4c, 4c+4] (chunk 7 clamps the 5th read
// to frame 31), owns moments for frames 4c..4c+3 and pairs 4c..4c+3
// (chunk 7: 28..30). Same ownership template as r2/r7 (verified-passing).
template<int BYTEFMT>
__launch_bounds__(256)
__global__ void pass1_kernel(const float* __restrict__ pred,
                             const float* __restrict__ depth,
                             const void*  __restrict__ maskp,
                             double* __restrict__ partials,
                             int*    __restrict__ cnt,
                             float*  __restrict__ rbuf,
                             float*  __restrict__ gbuf,
                             float*  __restrict__ out)
{
    // zero out before rowquant (stream-ordered; replaces a memset dispatch)
    if (blockIdx.x == 0 && blockIdx.y == 0 && threadIdx.x == 0) out[0] = 0.0f;

    const int p4 = blockIdx.x * 256 + threadIdx.x;
    const bool active = (p4 < HW4);
    const int p4c = active ? p4 : (HW4 - 1);       // clamp; masked out below
    const int b = blockIdx.y >> 3;
    const int c = blockIdx.y & 7;
    const int fs = c * 4;                           // first frame of chunk
    const size_t base = (size_t)b * T_ * HW + (size_t)fs * HW + (size_t)p4c * 4;

    const float* pp = pred + base;
    const float* dd = depth + base;
    const unsigned char* m8 = (const unsigned char*)maskp + base;  // 1 B/elem
    const int* m32 = (const int*)maskp + base;                     // 4 B/elem

    // ---- full-chunk prefetch: all 5 frames, static indices ----
    // 5th read clamps to frame 31 for chunk 7 (its pair is unowned anyway)
    const size_t off4 = (size_t)((c == 7) ? 3 : 4) * HW;
    fx4 pvs[NFC], dvs[NFC];
    unsigned int mws[NFC];
    ix4 mis[NFC];
    #pragma unroll
    for (int k = 0; k < NFC; ++k) {
        const size_t off = (k < 4) ? (size_t)k * HW : off4;
        pvs[k] = nt_load4(pp + off);
        dvs[k] = nt_load4(dd + off);
        if (BYTEFMT) mws[k] = nt_loadu(m8 + off);
        else         mis[k] = nt_load4i(m32 + off);
    }

    int scn = 0;
    float f_r = 0.f, f_g = 0.f, f_rg = 0.f, f_rr = 0.f;
    float pcr[4], pcg[4], pcd[4];
    unsigned int pmb = 0u;

    #pragma unroll
    for (int k = 0; k < NFC; ++k) {
        unsigned int mb;
        if (BYTEFMT) {
            const unsigned int w = mws[k];
            mb = ((w & 0x000000FFu) ? 1u : 0u) | ((w & 0x0000FF00u) ? 2u : 0u)
               | ((w & 0x00FF0000u) ? 4u : 0u) | ((w & 0xFF000000u) ? 8u : 0u);
        } else {
            const ix4 mi = mis[k];
            mb = (mi.x ? 1u : 0u) | (mi.y ? 2u : 0u) | (mi.z ? 4u : 0u) | (mi.w ? 8u : 0u);
        }
        if (!active) mb = 0u;

        const float px[4] = {pvs[k].x, pvs[k].y, pvs[k].z, pvs[k].w};
        const float dx[4] = {dvs[k].x, dvs[k].y, dvs[k].z, dvs[k].w};
        float cr[4], cg[4], cd[4];
        #pragma unroll
        for (int j = 0; j < 4; ++j) {
            cr[j] = fmaxf(px[j], EPSF);
            cd[j] = dx[j];
            cg[j] = fast_rcp(fmaxf(dx[j], EPSF));
        }

        // moments: chunk owns local frames 0..3 (all 32 covered exactly once)
        if (k <= 3) {
            #pragma unroll
            for (int j = 0; j < 4; ++j) {
                const bool m = (mb >> j) & 1u;
                const float rm = m ? cr[j] : 0.0f;
                const float gm = m ? cg[j] : 0.0f;
                scn += m ? 1 : 0;
                f_r += rm; f_g += gm;
                f_rg = fmaf(rm, gm, f_rg);
                f_rr = fmaf(rm, rm, f_rr);
            }
        }

        // pair (fs+k-1, fs+k): k=1..4; chunk 7 has no k=4 pair
        if (k >= 1 && (k <= 3 || c < 7)) {
            const int row = b * NPAIR + fs + k - 1;
            #pragma unroll
            for (int j = 0; j < 4; ++j) {
                if (((mb >> j) & (pmb >> j) & 1u) && fabsf(cd[j] - pcd[j]) < STH) {
                    const int pos = atomicAdd(&cnt[row * CSTR], 1);
                    if (pos < CAP) {
                        rbuf[row * CAP + pos] = fabsf(cr[j] - pcr[j]);
                        gbuf[row * CAP + pos] = fabsf(cg[j] - pcg[j]);
                    }
                }
            }
        }

        #pragma unroll
        for (int j = 0; j < 4; ++j) { pcr[j] = cr[j]; pcg[j] = cg[j]; pcd[j] = cd[j]; }
        pmb = mb;
    }

    // ---- fp64 from here: wave reduce -> LDS -> per-block partial ----
    double v1 = (double)f_r, v2 = (double)f_g, v3 = (double)f_rg, v4 = (double)f_rr;
    int vc = scn;
    #pragma unroll
    for (int o = 32; o > 0; o >>= 1) {
        v1 += __shfl_down(v1, o); v2 += __shfl_down(v2, o);
        v3 += __shfl_down(v3, o); v4 += __shfl_down(v4, o);
        vc += __shfl_down(vc, o);
    }
    __shared__ double red[4][4];
    __shared__ int redc[4];
    const int wid = threadIdx.x >> 6, lane = threadIdx.x & 63;
    if (lane == 0) { red[wid][0]=v1; red[wid][1]=v2; red[wid][2]=v3; red[wid][3]=v4; redc[wid]=vc; }
    __syncthreads();
    if (threadIdx.x == 0) {
        double* p = partials + (size_t)(blockIdx.y * GX + blockIdx.x) * 5;
        p[0] = (double)(redc[0] + redc[1] + redc[2] + redc[3]);
        p[1] = red[0][0]+red[1][0]+red[2][0]+red[3][0];
        p[2] = red[0][1]+red[1][1]+red[2][1]+red[3][1];
        p[3] = red[0][2]+red[1][2]+red[2][2]+red[3][2];
        p[4] = red[0][3]+red[1][3]+red[2][3]+red[3][3];
    }
}

// One block per row: reduce this batch's partials (redundant across blocks),
// solve |s| (shift cancels in temporal diffs), bitonic sort, linear-interp
// quantile, trimmed mean, one fp32 atomicAdd of loss/NROW into d_out.
__launch_bounds__(256)
__global__ void rowquant_kernel(const double* __restrict__ partials,
                                const int* __restrict__ cnt,
                                const float* __restrict__ rbuf,
                                const float* __restrict__ gbuf,
                                float* __restrict__ out)
{
    __shared__ float arr[CAP];
    __shared__ double rs[4][5];
    __shared__ float s_sa;
    __shared__ int   s_P;
    const int row = blockIdx.x;
    const int bb  = row / NPAIR;
    const int wid = threadIdx.x >> 6, lane = threadIdx.x & 63;

    // ---- reduce partials for this batch (8 chunks x GX, contiguous) ----
    const double* p = partials + (size_t)bb * NBLKB * 5;
    double v[5] = {0, 0, 0, 0, 0};
    for (int i = threadIdx.x; i < NBLKB; i += 256) {
        #pragma unroll
        for (int j = 0; j < 5; ++j) v[j] += p[i * 5 + j];
    }
    #pragma unroll
    for (int o = 32; o > 0; o >>= 1) {
        #pragma unroll
        for (int j = 0; j < 5; ++j) v[j] += __shfl_down(v[j], o);
    }
    if (lane == 0) {
        #pragma unroll
        for (int j = 0; j < 5; ++j) rs[wid][j] = v[j];
    }
    __syncthreads();

    int n = cnt[row * CSTR]; if (n > CAP) n = CAP;
    if (threadIdx.x == 0) {
        const double c0  = rs[0][0]+rs[1][0]+rs[2][0]+rs[3][0];
        const double sr  = rs[0][1]+rs[1][1]+rs[2][1]+rs[3][1];
        const double sg  = rs[0][2]+rs[1][2]+rs[2][2]+rs[3][2];
        const double srg = rs[0][3]+rs[1][3]+rs[2][3]+rs[3][3];
        const double srr = rs[0][4]+rs[1][4]+rs[2][4]+rs[3][4];
        const double count = fmax(c0, 1.0);
        const double mr = sr / count, mg = sg / count;
        const double cov = srg - mr * sg - mg * sr + c0 * mr * mg;
        double       var = srr - 2.0 * mr * sr + c0 * mr * mr;
        var = fmax(var, 1e-6);
        s_sa = (float)fabs(cov / var);
        int P = 64; while (P < n) P <<= 1;   // next pow2 >= n
        s_P = P;
    }
    __syncthreads();
    const float sa = s_sa;
    const int   P  = s_P;

    for (int i = threadIdx.x; i < P; i += 256) {
        float e = INFINITY;
        if (i < n) e = fabsf(sa * rbuf[row * CAP + i] - gbuf[row * CAP + i]);
        arr[i] = e;
    }
    __syncthreads();

    for (int k = 2; k <= P; k <<= 1) {
        for (int j = k >> 1; j > 0; j >>= 1) {
            for (int i = threadIdx.x; i < P; i += 256) {
                const int ij = i ^ j;
                if (ij > i) {
                    const float a = arr[i], bv = arr[ij];
                    const bool up = ((i & k) == 0);
                    if ((a > bv) == up) { arr[i] = bv; arr[ij] = a; }
                }
            }
            __syncthreads();
        }
    }

    __shared__ float sthresh;
    if (threadIdx.x == 0) {
        if (n > 0) {
            const float pos  = 0.8f * (float)(n - 1);
            const int   lo   = (int)floorf(pos);
            const int   hi   = (int)ceilf(pos);
            const float frac = pos - (float)lo;
            sthresh = arr[lo] * (1.0f - frac) + arr[hi] * frac;
        } else {
            sthresh = -1.0f;   // empty row -> keep nothing -> loss 0
        }
    }
    __syncthreads();
    const float th = sthresh;

    double lsum = 0.0; int lcnt = 0;
    for (int i = threadIdx.x; i < n; i += 256) {
        const float e = arr[i];
        if (e <= th) { lsum += (double)e; lcnt++; }
    }
    #pragma unroll
    for (int o = 32; o > 0; o >>= 1) { lsum += __shfl_down(lsum, o); lcnt += __shfl_down(lcnt, o); }
    __shared__ double rr2[4]; __shared__ int rc2[4];
    if (lane == 0) { rr2[wid] = lsum; rc2[wid] = lcnt; }
    __syncthreads();
    if (threadIdx.x == 0) {
        const double tot = rr2[0] + rr2[1] + rr2[2] + rr2[3];
        const int    tc  = rc2[0] + rc2[1] + rc2[2] + rc2[3];
        const double loss_row = tot / (double)(tc > 0 ? tc : 1);
        atomicAdd(out, (float)(loss_row * (1.0 / (double)NROW)));
    }
}

extern "C" void kernel_launch(void* const* d_in, const int* in_sizes, int n_in,
                              void* d_out, int out_size, void* d_ws, size_t ws_size,
                              hipStream_t stream) {
    const float* pred  = (const float*)d_in[0];
    const float* depth = (const float*)d_in[1];
    const void*  mask  = d_in[2];
    float* out = (float*)d_out;

    char* ws = (char*)d_ws;
    int*    cnt        = (int*)(ws + 64);
    double* partials   = (double*)(ws + 8192);
    float*  rbuf       = (float*)(ws + 180224);
    float*  gbuf       = (float*)(ws + 688128);

    // mask format from input byte sizes (r2-verified: byte-packed bool is
    // 1/4 the byte size of the float inputs)
    const int byteFmt = (in_sizes[2] != in_sizes[0]) ? 1 : 0;

    // zero cnt [64, 4032); out is zeroed by pass1 (stream-ordered)
    hipMemsetAsync(ws + 64, 0, 3968, stream);

    dim3 g1(GX, B_ * CHUNKS);             // 263 x 16 = 4208 blocks
    if (byteFmt)
        pass1_kernel<1><<<g1, 256, 0, stream>>>(pred, depth, mask, partials, cnt, rbuf, gbuf, out);
    else
        pass1_kernel<0><<<g1, 256, 0, stream>>>(pred, depth, mask, partials, cnt, rbuf, gbuf, out);
    rowquant_kernel<<<NROW, 256, 0, stream>>>(partials, cnt, rbuf, gbuf, out);
}

// Round 9
// 200.596 us; speedup vs baseline: 1.0256x; 1.0256x over previous
//
#include <hip/hip_runtime.h>
#include <math.h>

#define HW      268324      // 518*518
#define HW4     67081       // HW/4 (pixel-quads per frame)
#define T_      32
#define B_      2
#define NPAIR   31          // T-1
#define NROW    62          // B*(T-1)
#define GX      263         // x-blocks: ceil(HW4/256)
#define CHUNKS  4           // frame-chunks per batch
#define NBLKB   (CHUNKS*GX) // partial-blocks per batch
#define NFC     9           // frames read per chunk (last chunk clamps 8 -> 7)
#define SLOTS   4           // rotating prefetch slots (depth 3)
#define CAP     2048        // per-row static-pixel capacity (~215 expected)
#define CSTR    16          // cnt stride in ints (64B line per counter)
#define EPSF    1e-6f
#define STH     0.05f

// native clang vector types — required by __builtin_nontemporal_load
typedef float fx4 __attribute__((ext_vector_type(4)));
typedef int   ix4 __attribute__((ext_vector_type(4)));

// ---- workspace layout (bytes) ----
// 64     : int    cnt[NROW*CSTR]        (zeroed by memset)   [64, 4032)
// 8192   : double partials[8*GX][5]                          [8192, 92352)
// 180224 : float  rbuf[NROW*CAP]
// 688128 : float  gbuf[NROW*CAP]

// FINAL CONFIG (r7, best measured: 203.3 us total; pass1 47.7 us).
// Ceiling evidence (r6/r7/r8 sweep): occupancy 4.8/9.1/14.7 waves/CU gave
// logical BW 3.13/3.66/3.90 TB/s — saturating an on-chip request-path
// ceiling ~3.9 TB/s for this 3-stream 1MB-strided pattern. Duration is
// HBM-invariant (warm-L3 replays identical to cold in r0/r2/r5/r8), so the
// HBM roofline (24.5 us) is not binding. pass1 floor = 174 MB logical /
// 3.9 TB/s ~= 45 us; measured 47.7 (+6%). Remaining total is rowquant
// (~15 us) + fixed harness reset traffic (~140 us, dispatch-count-invariant
// per r0/r2/r4).

// reciprocal: v_rcp_f32 + 1 Newton step (~1 ulp); tolerance is 2% relative
__device__ __forceinline__ float fast_rcp(float x) {
    float r = __builtin_amdgcn_rcpf(x);
    float e = fmaf(-x, r, 1.0f);
    return fmaf(r, e, r);
}

// NT loads: proven in every best config; duration is HBM-independent (warm
// L3 replays take the same time), so streaming no-allocate is right.
__device__ __forceinline__ fx4 nt_load4(const float* p) {
    return __builtin_nontemporal_load((const fx4*)p);
}
__device__ __forceinline__ ix4 nt_load4i(const int* p) {
    return __builtin_nontemporal_load((const ix4*)p);
}
__device__ __forceinline__ unsigned int nt_loadu(const unsigned char* p) {
    return __builtin_nontemporal_load((const unsigned int*)p);
}

// Quarter-chunk pass1: chunk c of batch b reads frames [8c, 8c+8] (last
// chunk clamps the 9th read to frame 31), owns moments for frames 8c..8c+7
// and pairs 8c..8c+7 (chunk 3: 24..30). 2104 blocks, depth-3 rotating
// prefetch, compile-time mask format.
//
// TOOLCHAIN LANDMINE (r3/r4/r5-measured): a min-waves 2nd launch_bounds arg
// makes the backend chase ~2x the requested occupancy and spill the loop
// body. Single-arg launch_bounds(256) is safe.
template<int BYTEFMT>
__launch_bounds__(256)
__global__ void pass1_kernel(const float* __restrict__ pred,
                             const float* __restrict__ depth,
                             const void*  __restrict__ maskp,
                             double* __restrict__ partials,
                             int*    __restrict__ cnt,
                             float*  __restrict__ rbuf,
                             float*  __restrict__ gbuf,
                             float*  __restrict__ out)
{
    // zero out before rowquant (stream-ordered; replaces a memset dispatch)
    if (blockIdx.x == 0 && blockIdx.y == 0 && threadIdx.x == 0) out[0] = 0.0f;

    const int p4 = blockIdx.x * 256 + threadIdx.x;
    const bool active = (p4 < HW4);
    const int p4c = active ? p4 : (HW4 - 1);       // clamp; masked out below
    const int b = blockIdx.y >> 2;
    const int c = blockIdx.y & 3;
    const int fs = c * 8;                           // first frame of chunk
    const size_t base = (size_t)b * T_ * HW + (size_t)fs * HW + (size_t)p4c * 4;
    // local offset of the 9th read (chunk 3 re-reads frame 31; pair unowned)
    const size_t off8 = (size_t)((c == 3) ? 7 : 8) * HW;

    const float* pp = pred + base;
    const float* dd = depth + base;
    const unsigned char* m8 = (const unsigned char*)maskp + base;  // 1 B/elem
    const int* m32 = (const int*)maskp + base;                     // 4 B/elem

    fx4 pvs[SLOTS], dvs[SLOTS];
    unsigned int mws[SLOTS];
    ix4 mis[SLOTS];

    // ---- prologue: prefetch local frames 0..2 ----
    #pragma unroll
    for (int k = 0; k < SLOTS - 1; ++k) {
        pvs[k] = nt_load4(pp + (size_t)k * HW);
        dvs[k] = nt_load4(dd + (size_t)k * HW);
        if (BYTEFMT) mws[k] = nt_loadu(m8 + (size_t)k * HW);
        else         mis[k] = nt_load4i(m32 + (size_t)k * HW);
    }

    int scn = 0;
    float f_r = 0.f, f_g = 0.f, f_rg = 0.f, f_rr = 0.f;
    float pcr[4], pcg[4], pcd[4];
    unsigned int pmb = 0u;

    #pragma unroll
    for (int k = 0; k < NFC; ++k) {
        // prefetch local frame k+3 (the 9th read uses the clamped offset)
        const int kp = k + SLOTS - 1;
        if (kp < NFC) {
            const size_t off = (kp < 8) ? (size_t)kp * HW : off8;
            const int s2 = kp % SLOTS;
            pvs[s2] = nt_load4(pp + off);
            dvs[s2] = nt_load4(dd + off);
            if (BYTEFMT) mws[s2] = nt_loadu(m8 + off);
            else         mis[s2] = nt_load4i(m32 + off);
        }
        const int s = k % SLOTS;
        unsigned int mb;
        if (BYTEFMT) {
            const unsigned int w = mws[s];
            mb = ((w & 0x000000FFu) ? 1u : 0u) | ((w & 0x0000FF00u) ? 2u : 0u)
               | ((w & 0x00FF0000u) ? 4u : 0u) | ((w & 0xFF000000u) ? 8u : 0u);
        } else {
            const ix4 mi = mis[s];
            mb = (mi.x ? 1u : 0u) | (mi.y ? 2u : 0u) | (mi.z ? 4u : 0u) | (mi.w ? 8u : 0u);
        }
        if (!active) mb = 0u;

        const float px[4] = {pvs[s].x, pvs[s].y, pvs[s].z, pvs[s].w};
        const float dx[4] = {dvs[s].x, dvs[s].y, dvs[s].z, dvs[s].w};
        float cr[4], cg[4], cd[4];
        #pragma unroll
        for (int j = 0; j < 4; ++j) {
            cr[j] = fmaxf(px[j], EPSF);
            cd[j] = dx[j];
            cg[j] = fast_rcp(fmaxf(dx[j], EPSF));
        }

        // moments: chunk owns local frames 0..7 (all 32 covered exactly once)
        if (k <= 7) {
            #pragma unroll
            for (int j = 0; j < 4; ++j) {
                const bool m = (mb >> j) & 1u;
                const float rm = m ? cr[j] : 0.0f;
                const float gm = m ? cg[j] : 0.0f;
                scn += m ? 1 : 0;
                f_r += rm; f_g += gm;
                f_rg = fmaf(rm, gm, f_rg);
                f_rr = fmaf(rm, rm, f_rr);
            }
        }

        // pair (fs+k-1, fs+k): k=1..8; chunk 3 has no k=8 pair
        if (k >= 1 && (k <= 7 || c < 3)) {
            const int row = b * NPAIR + fs + k - 1;
            #pragma unroll
            for (int j = 0; j < 4; ++j) {
                if (((mb >> j) & (pmb >> j) & 1u) && fabsf(cd[j] - pcd[j]) < STH) {
                    const int pos = atomicAdd(&cnt[row * CSTR], 1);
                    if (pos < CAP) {
                        rbuf[row * CAP + pos] = fabsf(cr[j] - pcr[j]);
                        gbuf[row * CAP + pos] = fabsf(cg[j] - pcg[j]);
                    }
                }
            }
        }

        #pragma unroll
        for (int j = 0; j < 4; ++j) { pcr[j] = cr[j]; pcg[j] = cg[j]; pcd[j] = cd[j]; }
        pmb = mb;
    }

    // ---- fp64 from here: wave reduce -> LDS -> per-block partial ----
    double v1 = (double)f_r, v2 = (double)f_g, v3 = (double)f_rg, v4 = (double)f_rr;
    int vc = scn;
    #pragma unroll
    for (int o = 32; o > 0; o >>= 1) {
        v1 += __shfl_down(v1, o); v2 += __shfl_down(v2, o);
        v3 += __shfl_down(v3, o); v4 += __shfl_down(v4, o);
        vc += __shfl_down(vc, o);
    }
    __shared__ double red[4][4];
    __shared__ int redc[4];
    const int wid = threadIdx.x >> 6, lane = threadIdx.x & 63;
    if (lane == 0) { red[wid][0]=v1; red[wid][1]=v2; red[wid][2]=v3; red[wid][3]=v4; redc[wid]=vc; }
    __syncthreads();
    if (threadIdx.x == 0) {
        double* p = partials + (size_t)(blockIdx.y * GX + blockIdx.x) * 5;
        p[0] = (double)(redc[0] + redc[1] + redc[2] + redc[3]);
        p[1] = red[0][0]+red[1][0]+red[2][0]+red[3][0];
        p[2] = red[0][1]+red[1][1]+red[2][1]+red[3][1];
        p[3] = red[0][2]+red[1][2]+red[2][2]+red[3][2];
        p[4] = red[0][3]+red[1][3]+red[2][3]+red[3][3];
    }
}

// One block per row: reduce this batch's partials (redundant across blocks),
// solve |s| (shift cancels in temporal diffs), bitonic sort, linear-interp
// quantile, trimmed mean, one fp32 atomicAdd of loss/NROW into d_out.
__launch_bounds__(256)
__global__ void rowquant_kernel(const double* __restrict__ partials,
                                const int* __restrict__ cnt,
                                const float* __restrict__ rbuf,
                                const float* __restrict__ gbuf,
                                float* __restrict__ out)
{
    __shared__ float arr[CAP];
    __shared__ double rs[4][5];
    __shared__ float s_sa;
    __shared__ int   s_P;
    const int row = blockIdx.x;
    const int bb  = row / NPAIR;
    const int wid = threadIdx.x >> 6, lane = threadIdx.x & 63;

    // ---- reduce partials for this batch (4 chunks x GX, contiguous) ----
    const double* p = partials + (size_t)bb * NBLKB * 5;
    double v[5] = {0, 0, 0, 0, 0};
    for (int i = threadIdx.x; i < NBLKB; i += 256) {
        #pragma unroll
        for (int j = 0; j < 5; ++j) v[j] += p[i * 5 + j];
    }
    #pragma unroll
    for (int o = 32; o > 0; o >>= 1) {
        #pragma unroll
        for (int j = 0; j < 5; ++j) v[j] += __shfl_down(v[j], o);
    }
    if (lane == 0) {
        #pragma unroll
        for (int j = 0; j < 5; ++j) rs[wid][j] = v[j];
    }
    __syncthreads();

    int n = cnt[row * CSTR]; if (n > CAP) n = CAP;
    if (threadIdx.x == 0) {
        const double c0  = rs[0][0]+rs[1][0]+rs[2][0]+rs[3][0];
        const double sr  = rs[0][1]+rs[1][1]+rs[2][1]+rs[3][1];
        const double sg  = rs[0][2]+rs[1][2]+rs[2][2]+rs[3][2];
        const double srg = rs[0][3]+rs[1][3]+rs[2][3]+rs[3][3];
        const double srr = rs[0][4]+rs[1][4]+rs[2][4]+rs[3][4];
        const double count = fmax(c0, 1.0);
        const double mr = sr / count, mg = sg / count;
        const double cov = srg - mr * sg - mg * sr + c0 * mr * mg;
        double       var = srr - 2.0 * mr * sr + c0 * mr * mr;
        var = fmax(var, 1e-6);
        s_sa = (float)fabs(cov / var);
        int P = 64; while (P < n) P <<= 1;   // next pow2 >= n
        s_P = P;
    }
    __syncthreads();
    const float sa = s_sa;
    const int   P  = s_P;

    for (int i = threadIdx.x; i < P; i += 256) {
        float e = INFINITY;
        if (i < n) e = fabsf(sa * rbuf[row * CAP + i] - gbuf[row * CAP + i]);
        arr[i] = e;
    }
    __syncthreads();

    for (int k = 2; k <= P; k <<= 1) {
        for (int j = k >> 1; j > 0; j >>= 1) {
            for (int i = threadIdx.x; i < P; i += 256) {
                const int ij = i ^ j;
                if (ij > i) {
                    const float a = arr[i], bv = arr[ij];
                    const bool up = ((i & k) == 0);
                    if ((a > bv) == up) { arr[i] = bv; arr[ij] = a; }
                }
            }
            __syncthreads();
        }
    }

    __shared__ float sthresh;
    if (threadIdx.x == 0) {
        if (n > 0) {
            const float pos  = 0.8f * (float)(n - 1);
            const int   lo   = (int)floorf(pos);
            const int   hi   = (int)ceilf(pos);
            const float frac = pos - (float)lo;
            sthresh = arr[lo] * (1.0f - frac) + arr[hi] * frac;
        } else {
            sthresh = -1.0f;   // empty row -> keep nothing -> loss 0
        }
    }
    __syncthreads();
    const float th = sthresh;

    double lsum = 0.0; int lcnt = 0;
    for (int i = threadIdx.x; i < n; i += 256) {
        const float e = arr[i];
        if (e <= th) { lsum += (double)e; lcnt++; }
    }
    #pragma unroll
    for (int o = 32; o > 0; o >>= 1) { lsum += __shfl_down(lsum, o); lcnt += __shfl_down(lcnt, o); }
    __shared__ double rr2[4]; __shared__ int rc2[4];
    if (lane == 0) { rr2[wid] = lsum; rc2[wid] = lcnt; }
    __syncthreads();
    if (threadIdx.x == 0) {
        const double tot = rr2[0] + rr2[1] + rr2[2] + rr2[3];
        const int    tc  = rc2[0] + rc2[1] + rc2[2] + rc2[3];
        const double loss_row = tot / (double)(tc > 0 ? tc : 1);
        atomicAdd(out, (float)(loss_row * (1.0 / (double)NROW)));
    }
}

extern "C" void kernel_launch(void* const* d_in, const int* in_sizes, int n_in,
                              void* d_out, int out_size, void* d_ws, size_t ws_size,
                              hipStream_t stream) {
    const float* pred  = (const float*)d_in[0];
    const float* depth = (const float*)d_in[1];
    const void*  mask  = d_in[2];
    float* out = (float*)d_out;

    char* ws = (char*)d_ws;
    int*    cnt        = (int*)(ws + 64);
    double* partials   = (double*)(ws + 8192);
    float*  rbuf       = (float*)(ws + 180224);
    float*  gbuf       = (float*)(ws + 688128);

    // mask format from input byte sizes (r2-verified: byte-packed bool is
    // 1/4 the byte size of the float inputs)
    const int byteFmt = (in_sizes[2] != in_sizes[0]) ? 1 : 0;

    // zero cnt [64, 4032); out is zeroed by pass1 (stream-ordered)
    hipMemsetAsync(ws + 64, 0, 3968, stream);

    dim3 g1(GX, B_ * CHUNKS);             // 263 x 8 = 2104 blocks
    if (byteFmt)
        pass1_kernel<1><<<g1, 256, 0, stream>>>(pred, depth, mask, partials, cnt, rbuf, gbuf, out);
    else
        pass1_kernel<0><<<g1, 256, 0, stream>>>(pred, depth, mask, partials, cnt, rbuf, gbuf, out);
    rowquant_kernel<<<NROW, 256, 0, stream>>>(partials, cnt, rbuf, gbuf, out);
}